// Round 9
// baseline (872.274 us; speedup 1.0000x reference)
//
#include <hip/hip_runtime.h>
#include <hip/hip_bf16.h>

typedef unsigned int u32;
typedef _Float16     f16;
typedef f16   f16x8v __attribute__((ext_vector_type(8)));
typedef f16   f16x4v __attribute__((ext_vector_type(4)));
typedef float f32x4  __attribute__((ext_vector_type(4)));

#define GX_BYTES ((size_t)65536 * 1024 * 2)

__device__ __forceinline__ float sigm(float x) {
    return __builtin_amdgcn_rcpf(1.0f + __expf(-x));
}
__device__ __forceinline__ float tanh_f(float x) {
    return 1.0f - 2.0f * __builtin_amdgcn_rcpf(__expf(2.0f * x) + 1.0f);
}
__device__ __forceinline__ f16x8v pack8(float4 a, float4 b) {
    f16x8v v;
    v[0] = (f16)a.x; v[1] = (f16)a.y; v[2] = (f16)a.z; v[3] = (f16)a.w;
    v[4] = (f16)b.x; v[5] = (f16)b.y; v[6] = (f16)b.z; v[7] = (f16)b.w;
    return v;
}

// ---------------------------------------------------------------------------
// Kernel 1: gates_x = x @ Wg[:, :256]^T + bg  -> f16, INTERLEAVED layout
// gx[m][unit*4 + gate] (gate: 0=f,1=i,2=c,3=o) so the recurrence reads one
// 8 B f16x4 per lane per step instead of 4 strided scalars.
// Also zeroes the 256 KB mailbox each replay (stale-tag protection).
// ---------------------------------------------------------------------------
__global__ __launch_bounds__(256) void gemm_gx(
    const float* __restrict__ X,
    const float* __restrict__ Wf, const float* __restrict__ Wi,
    const float* __restrict__ Wc, const float* __restrict__ Wo,
    const float* __restrict__ bf_, const float* __restrict__ bi_,
    const float* __restrict__ bc_, const float* __restrict__ bo_,
    f16* __restrict__ gx, u32* __restrict__ hx) {
    __shared__ _Float16 As[128 * 40];
    __shared__ _Float16 Bs[128 * 40];
    __shared__ float bias_lds[128];

    const int tid = threadIdx.x;
    const int wgy = blockIdx.y;
    const size_t m0 = (size_t)blockIdx.x * 128;

    if (wgy == 0) {
        const int gid = blockIdx.x * 256 + tid;
        if (gid < 16384) {
            int4 z; z.x = 0; z.y = 0; z.z = 0; z.w = 0;
            ((int4*)hx)[gid] = z;
        }
    }

    const float* Wsel[4] = {Wf, Wi, Wc, Wo};
    const float* bsel[4] = {bf_, bi_, bc_, bo_};
    const float* Wseg = Wsel[wgy >> 1];
    const int gate    = wgy >> 1;
    const int row_off = (wgy & 1) * 128;

    if (tid < 128) bias_lds[tid] = bsel[gate][row_off + tid];

    const int r  = tid >> 2;
    const int c8 = (tid & 3) * 8;

    const float* Ap0 = X + (m0 + r) * 256 + c8;
    const float* Ap1 = Ap0 + 64 * 256;
    const float* Bp0 = Wseg + (size_t)(row_off + r) * 512 + c8;
    const float* Bp1 = Bp0 + 64 * 512;

    const int lane = tid & 63;
    const int w    = tid >> 6;
    const int wm = w >> 1, wn = w & 1;
    const int col = lane & 15, quad = lane >> 4;

    f32x4 acc[4][4] = {};

    for (int kc = 0; kc < 8; kc++) {
        const int kk = kc * 32;
        float4 a00 = *(const float4*)(Ap0 + kk);
        float4 a01 = *(const float4*)(Ap0 + kk + 4);
        float4 a10 = *(const float4*)(Ap1 + kk);
        float4 a11 = *(const float4*)(Ap1 + kk + 4);
        float4 b00 = *(const float4*)(Bp0 + kk);
        float4 b01 = *(const float4*)(Bp0 + kk + 4);
        float4 b10 = *(const float4*)(Bp1 + kk);
        float4 b11 = *(const float4*)(Bp1 + kk + 4);
        __syncthreads();
        *(f16x8v*)&As[r * 40 + c8]        = pack8(a00, a01);
        *(f16x8v*)&As[(r + 64) * 40 + c8] = pack8(a10, a11);
        *(f16x8v*)&Bs[r * 40 + c8]        = pack8(b00, b01);
        *(f16x8v*)&Bs[(r + 64) * 40 + c8] = pack8(b10, b11);
        __syncthreads();
        f16x8v a[4], b[4];
        #pragma unroll
        for (int i = 0; i < 4; i++)
            a[i] = *(const f16x8v*)&As[(wm * 64 + i * 16 + col) * 40 + quad * 8];
        #pragma unroll
        for (int j = 0; j < 4; j++)
            b[j] = *(const f16x8v*)&Bs[(wn * 64 + j * 16 + col) * 40 + quad * 8];
        #pragma unroll
        for (int i = 0; i < 4; i++)
            #pragma unroll
            for (int j = 0; j < 4; j++)
                acc[i][j] = __builtin_amdgcn_mfma_f32_16x16x32_f16(a[i], b[j], acc[i][j], 0, 0, 0);
    }

    #pragma unroll
    for (int i = 0; i < 4; i++) {
        #pragma unroll
        for (int j = 0; j < 4; j++) {
            #pragma unroll
            for (int rg = 0; rg < 4; rg++) {
                const size_t m = m0 + wm * 64 + i * 16 + quad * 4 + rg;
                const int nl = wn * 64 + j * 16 + col;
                const int unit = row_off + nl;
                gx[m * 1024 + (size_t)unit * 4 + gate] =
                    (f16)(acc[i][j][rg] + bias_lds[nl]);
            }
        }
    }
}

// ---------------------------------------------------------------------------
// Kernel 2: round-5 structure (champion, 627 us) + two targeted trims:
// (a) quad0-only mailbox traffic — early-issue, spin, and LDS stage all
//     guarded by quad==0: 4x fewer LLC poll requests chip-wide (512 -> 128
//     lanes/WG). All pairs spin in the same wall-clock window (lockstep),
//     so redundant poll load was pure LLC contention (round-2 mechanism,
//     milder dose). Wave timing unchanged (quads 1-3 wait via exec mask).
// (b) interleaved gx: one 8 B f16x4 load/lane/step instead of 4 scalars.
//
// Everything else identical to round 5: 256 WGs x 512 thr, WG (b, s) owns
// units [128s,128s+128); wave w owns 16 units x 4 gates; weights register-
// resident with static indices (wB[g][0..3] own-K, [4..7] remote-K);
// phase A (own-K, 16 MFMA) covers the early-issued partner-word load;
// tight spin on mismatch; tagged words (h<<16)|(t+1), relaxed agent
// atomics, 2-slot double buffer, zeroed each replay, bounded spin.
// ---------------------------------------------------------------------------
__global__ __launch_bounds__(512, 2) void lstm_rec(
    const float* __restrict__ Wf, const float* __restrict__ Wi,
    const float* __restrict__ Wc, const float* __restrict__ Wo,
    const f16* __restrict__ gx,
    const float* __restrict__ Wout, const float* __restrict__ bout,
    u32* hx,
    float* __restrict__ out) {
    __shared__ _Float16 hbuf[2][256] __attribute__((aligned(16)));

    const int tid  = threadIdx.x;
    const int bb   = blockIdx.x;
    const int b    = bb & 127;          // batch
    const int s    = bb >> 7;           // unit-half 0/1
    const int w    = tid >> 6;          // wave 0..7
    const int l    = tid & 63;
    const int l15  = l & 15;
    const int quad = l >> 4;

    const int u_loc = 16 * w + l15;     // 0..127 within our half
    const int u     = 128 * s + u_loc;  // absolute unit

    const int kOwn = 128 * s;           // h-column base of own half
    const int kRem = 128 * (1 - s);     // h-column base of remote half

    // --- register-resident B fragments, STATIC indices ---
    f16x8v wB[4][8];
    {
        const float* gp[4] = {Wf, Wi, Wc, Wo};
        #pragma unroll
        for (int g = 0; g < 4; g++) {
            const float* rowO = gp[g] + (size_t)u * 512 + 256 + kOwn + quad * 8;
            const float* rowR = gp[g] + (size_t)u * 512 + 256 + kRem + quad * 8;
            #pragma unroll
            for (int k = 0; k < 4; k++) {
                float4 x0 = *(const float4*)(rowO + k * 32);
                float4 x1 = *(const float4*)(rowO + k * 32 + 4);
                wB[g][k] = pack8(x0, x1);
                float4 y0 = *(const float4*)(rowR + k * 32);
                float4 y1 = *(const float4*)(rowR + k * 32 + 4);
                wB[g][4 + k] = pack8(y0, y1);
            }
        }
    }

    float c = 0.0f;
    if (tid < 256) hbuf[0][tid] = (f16)0.0f;   // h_0 = 0 (both halves)

    u32* pub = hx + (size_t)b * 512 + (size_t)s * 256;        // + slot*128 + u_loc
    u32* par = hx + (size_t)b * 512 + (size_t)(1 - s) * 256;  // partner's words

    // interleaved gx: lane's 4 gate values are 8 contiguous bytes
    const f16* gxr = gx + (size_t)b * 512 * 1024 + (size_t)u * 4;
    f16x4v gv = *(const f16x4v*)gxr;                 // t = 0
    float pf = (float)gv[0], pi_ = (float)gv[1];
    float pg = (float)gv[2], po  = (float)gv[3];

    const f32x4 Zc = {0.f, 0.f, 0.f, 0.f};

    __syncthreads();   // h_0 visible

    for (int t = 0; t < 512; t++) {
        const int cur = t & 1;
        const int nxt = cur ^ 1;

        // 1. EARLY-ISSUE the partner-word load — quad0 lanes only (the
        //    writers). 4x fewer LLC requests than all-lane polling.
        u32 rw = 0;
        if (quad == 0)
            rw = __hip_atomic_load(par + cur * 128 + u_loc,
                                   __ATOMIC_RELAXED, __HIP_MEMORY_SCOPE_AGENT);

        // 2. gx prefetch for next step (one 8 B load)
        f16x4v gn = *(const f16x4v*)(gxr + (size_t)(t < 511 ? t + 1 : 511) * 1024);

        // 3. Phase A: own-K contribution (no remote dependence)
        const _Float16* hOwn = &hbuf[cur][kOwn + quad * 8];
        f32x4 acc[4];
        #pragma unroll
        for (int k = 0; k < 4; k++) {
            f16x8v A = *(const f16x8v*)&hOwn[k * 32];
            if (k == 0) {
                #pragma unroll
                for (int g = 0; g < 4; g++)
                    acc[g] = __builtin_amdgcn_mfma_f32_16x16x32_f16(A, wB[g][0], Zc, 0, 0, 0);
            } else {
                #pragma unroll
                for (int g = 0; g < 4; g++)
                    acc[g] = __builtin_amdgcn_mfma_f32_16x16x32_f16(A, wB[g][k], acc[g], 0, 0, 0);
            }
        }

        // 4. Check the early load; tight spin only on mismatch (quad0 only;
        //    t=0 matches the zeroed mailbox's tag-0 words -> stages h_0=0).
        if (quad == 0) {
            const u32 want = (u32)t;
            int spin = 0;
            while ((rw & 0xFFFFu) != want && ++spin < (1 << 20))
                rw = __hip_atomic_load(par + cur * 128 + u_loc,
                                       __ATOMIC_RELAXED, __HIP_MEMORY_SCOPE_AGENT);
            hbuf[cur][kRem + u_loc] =
                __builtin_bit_cast(_Float16, (unsigned short)(rw >> 16));
        }
        __syncthreads();   // remote half of h_t staged

        // 5. Phase B: remote-K contribution
        const _Float16* hRem = &hbuf[cur][kRem + quad * 8];
        #pragma unroll
        for (int k = 0; k < 4; k++) {
            f16x8v A = *(const f16x8v*)&hRem[k * 32];
            #pragma unroll
            for (int g = 0; g < 4; g++)
                acc[g] = __builtin_amdgcn_mfma_f32_16x16x32_f16(A, wB[g][4 + k], acc[g], 0, 0, 0);
        }

        // 6. Elementwise (rows replicated -> reg 0 is this lane's unit)
        float F = pf + acc[0][0];
        float I = pi_ + acc[1][0];
        float G = pg + acc[2][0];
        float O = po + acc[3][0];
        float sf = sigm(F), si = sigm(I), so = sigm(O);
        float tg = tanh_f(G);
        c = c * sf + si * tg;
        float h = tanh_f(c) * so;

        const f16 h16v = (f16)h;
        if (quad == 0) {
            u32 word = ((u32)__builtin_bit_cast(unsigned short, h16v) << 16)
                     | (u32)(t + 1);
            __hip_atomic_store(pub + nxt * 128 + u_loc, word,
                               __ATOMIC_RELAXED, __HIP_MEMORY_SCOPE_AGENT);
            hbuf[nxt][u] = h16v;    // own half for next step
        }

        pf = (float)gn[0]; pi_ = (float)gn[1];
        pg = (float)gn[2]; po  = (float)gn[3];

        __syncthreads();   // own half of h_{t+1} visible; guards hbuf reuse
    }

    // Complete h_512: own half is in hbuf[0]; poll partner's tag-512 words.
    if (quad == 0) {
        u32 rw = __hip_atomic_load(par + 0 * 128 + u_loc,
                                   __ATOMIC_RELAXED, __HIP_MEMORY_SCOPE_AGENT);
        int spin = 0;
        while ((rw & 0xFFFFu) != 512u && ++spin < (1 << 20))
            rw = __hip_atomic_load(par + 0 * 128 + u_loc,
                                   __ATOMIC_RELAXED, __HIP_MEMORY_SCOPE_AGENT);
        hbuf[0][kRem + u_loc] =
            __builtin_bit_cast(_Float16, (unsigned short)(rw >> 16));
    }
    __syncthreads();

    // out[b, 64s:64s+64] = h_512 @ Wout^T + bout (both WGs have full h_512)
    if (tid < 64) {
        const int o = 64 * s + tid;
        float accv = bout[o];
        const float4* wv = (const float4*)(Wout + (size_t)o * 256);
        #pragma unroll
        for (int q = 0; q < 64; q++) {
            float4 v = wv[q];
            accv += v.x * (float)hbuf[0][q * 4 + 0];
            accv += v.y * (float)hbuf[0][q * 4 + 1];
            accv += v.z * (float)hbuf[0][q * 4 + 2];
            accv += v.w * (float)hbuf[0][q * 4 + 3];
        }
        out[(size_t)b * 128 + o] = accv;
    }
}

extern "C" void kernel_launch(void* const* d_in, const int* in_sizes, int n_in,
                              void* d_out, int out_size, void* d_ws, size_t ws_size,
                              hipStream_t stream) {
    const float* x    = (const float*)d_in[0];
    const float* Wf   = (const float*)d_in[1];
    const float* bfv  = (const float*)d_in[2];
    const float* Wi   = (const float*)d_in[3];
    const float* biv  = (const float*)d_in[4];
    const float* Wc   = (const float*)d_in[5];
    const float* bcv  = (const float*)d_in[6];
    const float* Wo   = (const float*)d_in[7];
    const float* bov  = (const float*)d_in[8];
    const float* Wout = (const float*)d_in[9];
    const float* bout = (const float*)d_in[10];

    f16* gx = (f16*)d_ws;
    u32* hx = (u32*)((char*)d_ws + GX_BYTES);   // 256 KB mailbox after gx

    gemm_gx<<<dim3(512, 8), 256, 0, stream>>>(x, Wf, Wi, Wc, Wo, bfv, biv, bcv, bov, gx, hx);
    lstm_rec<<<256, 512, 0, stream>>>(Wf, Wi, Wc, Wo, gx, Wout, bout, hx, (float*)d_out);
}